// Round 3
// baseline (499.980 us; speedup 1.0000x reference)
//
#include <hip/hip_runtime.h>
#include <stdint.h>

#define M_DIM 8192
#define N_DIM 4096
#define K_DIM 4096
#define NKT   (K_DIM / 64)

typedef __attribute__((ext_vector_type(4)))  float  floatx4;
typedef __attribute__((ext_vector_type(2)))  unsigned int uintx2;
typedef __attribute__((ext_vector_type(8)))  _Float16 halfx8;

// ---------------------------------------------------------------------------
// Conversion kernels, SPLIT and branch-free this round (diagnosis + ILP):
// distinct names so each shows its own rocprof row; no in-loop branch so the
// compiler unroll-jams 4 loads in flight. Coalesced: lane i loads float4 at
// base+i (1 KiB/wave-instr), stores 8 B (512 B/wave-instr, full lines).
// ---------------------------------------------------------------------------

#define A_F4 (M_DIM * K_DIM / 4)   // 8388608 float4 -> 16 iters/thread
#define W_F4 (N_DIM * K_DIM / 4)   // 4194304 float4 -> 8 iters/thread
#define CVT_BLOCKS 2048

__global__ __launch_bounds__(256) void cvt_a(const float* __restrict__ a_in,
                                             _Float16* __restrict__ a16) {
    const floatx4* a4 = (const floatx4*)a_in;
    uintx2* o2 = (uintx2*)a16;
    const int stride = CVT_BLOCKS * 256;
#pragma unroll 4
    for (int f = blockIdx.x * 256 + threadIdx.x; f < A_F4; f += stride) {
        floatx4 x = a4[f];
        union { _Float16 h[4]; uintx2 u; } p;
        p.h[0] = (_Float16)x[0]; p.h[1] = (_Float16)x[1];
        p.h[2] = (_Float16)x[2]; p.h[3] = (_Float16)x[3];
        o2[f] = p.u;
    }
}

__global__ __launch_bounds__(256) void cvt_w(const float* __restrict__ w_in,
                                             const float* __restrict__ scales,
                                             _Float16* __restrict__ w16) {
    const floatx4* w4 = (const floatx4*)w_in;
    uintx2* o2 = (uintx2*)w16;
    const int stride = CVT_BLOCKS * 256;
#pragma unroll 4
    for (int f = blockIdx.x * 256 + threadIdx.x; f < W_F4; f += stride) {
        const int o = f >> 10;                 // row (K_DIM/4 = 1024 f4/row)
        const int grp = (f & 1023) >> 5;       // k-group = (k*4)>>7
        const float s = scales[grp * N_DIM + o];
        floatx4 x = w4[f];
        union { _Float16 h[4]; uintx2 u; } p;
        p.h[0] = (_Float16)(x[0] * s); p.h[1] = (_Float16)(x[1] * s);
        p.h[2] = (_Float16)(x[2] * s); p.h[3] = (_Float16)(x[3] * s);
        o2[f] = p.u;
    }
}

// ---------------------------------------------------------------------------
// 256x256 8-phase GEMM, BK=64, 512 threads (8 waves as 2x4), 16x16x32 f16 MFMA.
// Counted vmcnt pipeline (verified r2: passed, bank conflicts 0, 1133 TF).
// NEW this round: XCD-aware bijective blockIdx swizzle. Grid = 512 blocks;
// HW round-robins linear id across 8 XCDs, so blocks with id%8==x share XCD x.
// Remap so XCD x owns a contiguous m-sweep over 2 n-panels: its B working set
// = 2 panels * 2 MiB = 4 MiB = one XCD's L2, A streams through shared L3.
// ---------------------------------------------------------------------------

__device__ __forceinline__ void gld_lds16(const _Float16* g, _Float16* l) {
    __builtin_amdgcn_global_load_lds(
        (const __attribute__((address_space(1))) void*)g,
        (__attribute__((address_space(3))) void*)l, 16, 0, 0);
}

#define WAITV(n) asm volatile("s_waitcnt vmcnt(" #n ")" ::: "memory")
#define BAR()    asm volatile("s_barrier" ::: "memory")

__device__ __forceinline__ void issue_half(const _Float16* gbase, _Float16* sbase,
                                           int b, int h, int kcol, int wid) {
#pragma unroll
    for (int q2 = 0; q2 < 2; ++q2) {
        const int q = 2 * h + q2;
        gld_lds16(gbase + (size_t)q * 64 * K_DIM + kcol,
                  sbase + b * 16384 + q * 4096 + wid * 512);
    }
}

__device__ __forceinline__ void load_a(halfx8 af[4][2], const _Float16* sA, int b,
                                       int ih, int wr, int l15, int sl0, int sl1) {
#pragma unroll
    for (int il = 0; il < 4; ++il) {
        const int ro = b * 16384 + (ih * 128 + il * 32 + wr * 16 + l15) * 64;
        af[il][0] = *(const halfx8*)&sA[ro + sl0];
        af[il][1] = *(const halfx8*)&sA[ro + sl1];
    }
}

__device__ __forceinline__ void load_b(halfx8 bf[2][2], const _Float16* sB, int b,
                                       int jh, int wc, int l15, int sl0, int sl1) {
#pragma unroll
    for (int jl = 0; jl < 2; ++jl) {
        const int ro = b * 16384 + (jh * 128 + jl * 64 + wc * 16 + l15) * 64;
        bf[jl][0] = *(const halfx8*)&sB[ro + sl0];
        bf[jl][1] = *(const halfx8*)&sB[ro + sl1];
    }
}

__device__ __forceinline__ void mfma_q(floatx4 acc[8][4], int ih, int jh,
                                       const halfx8 af[4][2], const halfx8 bf[2][2]) {
    __builtin_amdgcn_s_setprio(1);
#pragma unroll
    for (int il = 0; il < 4; ++il)
#pragma unroll
    for (int jl = 0; jl < 2; ++jl)
#pragma unroll
    for (int ks = 0; ks < 2; ++ks)
        acc[ih * 4 + il][jh * 2 + jl] = __builtin_amdgcn_mfma_f32_16x16x32_f16(
            af[il][ks], bf[jl][ks], acc[ih * 4 + il][jh * 2 + jl], 0, 0, 0);
    __builtin_amdgcn_s_setprio(0);
}

__global__ __launch_bounds__(512, 2) void gemm_f16(const _Float16* __restrict__ A,
                                                   const _Float16* __restrict__ B,
                                                   const float* __restrict__ bias,
                                                   float* __restrict__ C) {
    extern __shared__ _Float16 lds[];
    _Float16* sA = lds;                 // [2][256][64]
    _Float16* sB = lds + 2 * 256 * 64;  // [2][256][64]

    const int tid  = threadIdx.x;
    const int wid  = tid >> 6;
    const int lane = tid & 63;
    const int wr   = wid >> 2;          // 0..1
    const int wc   = wid & 3;           // 0..3
    const int l15  = lane & 15;
    const int lk   = lane >> 4;         // 0..3

    // XCD swizzle: lid%8 = XCD; give each XCD a contiguous m-sweep over 2
    // n-panels (B footprint 4 MiB = its L2).  512 % 8 == 0 -> bijective.
    const int lid = blockIdx.x;                 // 0..511
    const int swz = (lid & 7) * 64 + (lid >> 3);
    const int m0  = (swz & 31) * 256;
    const int n0  = (swz >> 5) * 256;

    // Staging: issue q covers rows q*64 + (tid>>3); slot tid&7 holds global
    // chunk (tid&7)^(row&7).  (q*64 ≡ 0 mod 8 -> offset constant across q.)
    const int rowt = tid >> 3;
    const int g8   = ((tid & 7) ^ ((tid >> 3) & 7)) * 8;
    const _Float16* Abase = A + (size_t)(m0 + rowt) * K_DIM + g8;
    const _Float16* Bbase = B + (size_t)(n0 + rowt) * K_DIM + g8;

    // Fragment read: chunk c = ks*4 + lk of row r lives at slot c^(r&7);
    // r&7 == lane&7 for all frag rows (bases are multiples of 16).
    const int sl0 = ((lk) ^ (lane & 7)) * 8;
    const int sl1 = sl0 ^ 32;

    floatx4 acc[8][4] = {};
    halfx8 af[4][2], bf0[2][2], bf1[2][2];

    // Prologue: stage kt=0 into buf 0 in wait-order A0, B0, B1, A1 (8 loads/wave).
    issue_half(Abase, sA, 0, 0, 0, wid);
    issue_half(Bbase, sB, 0, 0, 0, wid);
    issue_half(Bbase, sB, 0, 1, 0, wid);
    issue_half(Abase, sA, 0, 1, 0, wid);

    for (int kt = 0; kt < NKT - 1; ++kt) {
        const int b  = kt & 1;
        const int nb = b ^ 1;
        const int kn = (kt + 1) * 64;
        // P1: quadrant A0xB0; needs A0,B0(kt) -> oldest 4 ops of 8 in flight.
        WAITV(4); BAR();
        issue_half(Abase, sA, nb, 0, kn, wid);       // A0(kt+1)
        load_a(af, sA, b, 0, wr, l15, sl0, sl1);
        load_b(bf0, sB, b, 0, wc, l15, sl0, sl1);
        mfma_q(acc, 0, 0, af, bf0);
        // P2: A0xB1; needs B1(kt) -> vmcnt(4) leaves {A1(kt), A0(kt+1)}.
        WAITV(4); BAR();
        issue_half(Bbase, sB, nb, 0, kn, wid);       // B0(kt+1)
        load_b(bf1, sB, b, 1, wc, l15, sl0, sl1);
        mfma_q(acc, 0, 1, af, bf1);
        // P3: A1xB1; needs A1(kt) -> vmcnt(4) leaves {A0(kt+1), B0(kt+1)}.
        WAITV(4); BAR();
        issue_half(Bbase, sB, nb, 1, kn, wid);       // B1(kt+1)
        load_a(af, sA, b, 1, wr, l15, sl0, sl1);
        mfma_q(acc, 1, 1, af, bf1);
        // P4: A1xB0; all in registers -> no wait, no barrier.
        issue_half(Abase, sA, nb, 1, kn, wid);       // A1(kt+1)
        mfma_q(acc, 1, 0, af, bf0);
    }

    // Last K-tile: nothing left to issue; tighten the counts (4/2/0).
    {
        const int b = (NKT - 1) & 1;
        WAITV(4); BAR();
        load_a(af, sA, b, 0, wr, l15, sl0, sl1);
        load_b(bf0, sB, b, 0, wc, l15, sl0, sl1);
        mfma_q(acc, 0, 0, af, bf0);
        WAITV(2); BAR();
        load_b(bf1, sB, b, 1, wc, l15, sl0, sl1);
        mfma_q(acc, 0, 1, af, bf1);
        WAITV(0); BAR();
        load_a(af, sA, b, 1, wr, l15, sl0, sl1);
        mfma_q(acc, 1, 1, af, bf1);
        mfma_q(acc, 1, 0, af, bf0);
    }

    // Epilogue: 16x16 C/D layout col = lane&15, row = (lane>>4)*4 + reg.
#pragma unroll
    for (int jh = 0; jh < 2; ++jh)
#pragma unroll
    for (int jl = 0; jl < 2; ++jl) {
        const int n = n0 + jh * 128 + jl * 64 + wc * 16 + l15;
        const float bv = bias[n];
#pragma unroll
        for (int ih = 0; ih < 2; ++ih)
#pragma unroll
        for (int il = 0; il < 4; ++il) {
            const int mb = m0 + ih * 128 + il * 32 + wr * 16 + lk * 4;
            const floatx4 v = acc[ih * 4 + il][jh * 2 + jl];
#pragma unroll
            for (int r = 0; r < 4; ++r)
                C[(size_t)(mb + r) * N_DIM + n] = v[r] + bv;
        }
    }
}

// ---------------------------------------------------------------------------
// Exact fp32 fallback (only if workspace is too small) — slow but correct.
// ---------------------------------------------------------------------------

__global__ __launch_bounds__(256) void fallback_gemm(const float* __restrict__ A,
                                                     const float* __restrict__ W,
                                                     const float* __restrict__ S,
                                                     const float* __restrict__ bias,
                                                     float* __restrict__ C) {
    const long idx = (long)blockIdx.x * 256 + threadIdx.x;
    const int m = (int)(idx >> 12);
    const int n = (int)(idx & 4095);
    const float* a = A + (size_t)m * K_DIM;
    const float* w = W + (size_t)n * K_DIM;
    float acc = 0.f;
    for (int g = 0; g < 32; ++g) {
        const float s = S[g * N_DIM + n];
        float part = 0.f;
        const int kb = g * 128;
#pragma unroll 4
        for (int k = kb; k < kb + 128; ++k) part += a[k] * w[k];
        acc += part * s;
    }
    C[idx] = acc + bias[n];
}

// ---------------------------------------------------------------------------

extern "C" void kernel_launch(void* const* d_in, const int* in_sizes, int n_in,
                              void* d_out, int out_size, void* d_ws, size_t ws_size,
                              hipStream_t stream) {
    const float* input   = (const float*)d_in[0];
    const float* qweight = (const float*)d_in[1];
    const float* scales  = (const float*)d_in[2];
    const float* bias    = (const float*)d_in[3];
    float* out = (float*)d_out;

    const size_t a_bytes = (size_t)M_DIM * K_DIM * sizeof(_Float16); // 64 MiB
    const size_t w_bytes = (size_t)N_DIM * K_DIM * sizeof(_Float16); // 32 MiB

    if (ws_size >= a_bytes + w_bytes) {
        _Float16* a16 = (_Float16*)d_ws;
        _Float16* w16 = (_Float16*)((char*)d_ws + a_bytes);

        cvt_a<<<CVT_BLOCKS, 256, 0, stream>>>(input, a16);
        cvt_w<<<CVT_BLOCKS, 256, 0, stream>>>(qweight, scales, w16);

        // 128 KiB dynamic LDS: raise the per-kernel cap.
        static bool attr_done = false;
        if (!attr_done) {
            (void)hipFuncSetAttribute((const void*)gemm_f16,
                                      hipFuncAttributeMaxDynamicSharedMemorySize,
                                      131072);
            attr_done = true;
        }
        gemm_f16<<<dim3(512), 512, 131072, stream>>>(a16, w16, bias, out);
    } else {
        fallback_gemm<<<((size_t)M_DIM * N_DIM) / 256, 256, 0, stream>>>(
            input, qweight, scales, bias, out);
    }
}